// Round 20
// baseline (71.041 us; speedup 1.0000x reference)
//
#include <hip/hip_runtime.h>
#include <hip/hip_bf16.h>

#define M_ROWS 8192
#define K_DIM 128
#define NCLS 60
#define NSLOT 64           // 2 slots per 256-col panel (h-halves / source-row halves)
#define NSIM 528           // 32*33/2 upper-triangle panel pairs

// x = q_i . q_j where q = bf16(fhat * SCL), SCL^2 = 5*log2(e)  ->  sim = x*ln2, exp(sim) = 2^x
constexpr float SCL = 2.68579007f;     // sqrt(5 * 1.4426950408889634)
constexpr float LN2 = 0.69314718056f;

using f32x4 = __attribute__((ext_vector_type(4))) float;
using s16x8 = __attribute__((ext_vector_type(8))) short;

__device__ inline float bf2f(ushort u) {
    union { unsigned int i; float f; } v; v.i = ((unsigned int)u) << 16; return v.f;
}
__device__ inline float fexp2(float x) {
#if __has_builtin(__builtin_amdgcn_exp2f)
    return __builtin_amdgcn_exp2f(x);
#else
    return exp2f(x);
#endif
}

// packed fragment-major layout: ushort index = c16*2048 + kchunk*128 + lrow*8
//   (c16 = row/16 block, lrow = row%16, kchunk = k/8; one MFMA fragment per 64-lane load)

// ---------------- K1: 256 blocks x 32 rows: pure normalize -> fnr + fnp ----------------
__global__ __launch_bounds__(256) void kprep(const float* __restrict__ feat,
                                             ushort* __restrict__ fnr,
                                             ushort* __restrict__ fnp,
                                             float* __restrict__ out) {
    __shared__ __align__(16) ushort ln[32][128];   // 8 KB
    const int tid = threadIdx.x, wv = tid >> 6, lane = tid & 63;
    const int rbase = blockIdx.x * 32;

#pragma unroll
    for (int it = 0; it < 8; ++it) {
        const int r = wv * 8 + it;
        const int grow = rbase + r;
        const float2 v = *(const float2*)&feat[(size_t)grow * K_DIM + lane * 2];
        float ss = v.x * v.x + v.y * v.y;
#pragma unroll
        for (int m = 1; m < 64; m <<= 1) ss += __shfl_xor(ss, m, 64);
        const float rs = rsqrtf(ss) * SCL;
        __hip_bfloat16 ha = __float2bfloat16(v.x * rs);
        __hip_bfloat16 hb = __float2bfloat16(v.y * rs);
        ushort2 o;
        o.x = *reinterpret_cast<const ushort*>(&ha);
        o.y = *reinterpret_cast<const ushort*>(&hb);
        *(ushort2*)&fnr[(size_t)grow * K_DIM + lane * 2] = o;
        *(ushort2*)&ln[r][lane * 2] = o;
    }
    __syncthreads();
#pragma unroll
    for (int gb = 0; gb < 2; ++gb) {
        const s16x8 vv = *(const s16x8*)&ln[gb * 16 + (tid & 15)][(tid >> 4) * 8];
        *(s16x8*)&fnp[(size_t)(blockIdx.x * 2 + gb) * 2048 + tid * 8] = vv;
    }
    if (blockIdx.x == 0 && tid == 0) out[0] = 0.f;
}

// ---------------- K2: half-panel sim blocks (I,J,h) + class-gather tasks on blocks<60 ----------------
// 1056 blocks = 528 pairs x 2 col-halves. Row partials -> slot 2J+h (rows of I).
// Col partials (I<J): waves 0-3 -> slot 2I; waves 4-7 -> slot 2I+1, at rows J*256+h*128+0..127.
// Blocks 0-59 additionally compute S[c]/cntC[c] by direct label-scan gather over fnr.
__global__ __launch_bounds__(512) void kmain(const ushort* __restrict__ fnp,
                                             const ushort* __restrict__ fnr,
                                             const int* __restrict__ labels,
                                             float* __restrict__ denomP,
                                             float* __restrict__ S,
                                             float* __restrict__ cntC) {
    __shared__ __align__(16) ushort ldsB[8 * 2048];   // 32 KB: half-panel, packed layout
    __shared__ float colbuf[8][128];                  // 4 KB
    __shared__ float Sb[8][128];                      // 4 KB (class tail)
    __shared__ float Cb[8];
    const int tid = threadIdx.x;
    const int lane = tid & 63;
    const int lrow = lane & 15;
    const int g = lane >> 4;
    const int wv = tid >> 6;           // 0..7

    const int bid = blockIdx.x;
    const int p = bid >> 1;            // pair index 0..527
    const int h = bid & 1;             // column half
    // decode p -> (I, J), I <= J < 32; off(I) = 32I - I(I-1)/2
    int I = (int)((65.0f - sqrtf(4225.0f - 8.0f * (float)p)) * 0.5f);
    while ((I + 1) * 32 - ((I + 1) * I) / 2 <= p) ++I;
    while (I * 32 - (I * (I - 1)) / 2 > p) --I;
    const int J = I + (p - (I * 32 - (I * (I - 1)) / 2));
    const bool offd = (J != I);
    const int rbase = I * 256 + wv * 32;   // this wave's 32 rows

    // ---- stage half-panel (32 KB) into LDS; both sides linear ----
    {
        const ushort* gbase = fnp + (size_t)(J * 16 + h * 8) * 2048;
#pragma unroll
        for (int it = 0; it < 4; ++it) {
            const int chunk = it * 512 + wv * 64;      // wave-uniform; lane adds *16B
            const ushort* src = gbase + (size_t)(chunk + lane) * 8;
            ushort* dst = &ldsB[(size_t)chunk * 8];
            __builtin_amdgcn_global_load_lds((const __attribute__((address_space(1))) void*)src,
                                             (__attribute__((address_space(3))) void*)dst, 16, 0, 0);
        }
    }

    // persistent A fragments: rows rbase..+31, K=128 (packed, lane-linear, from global)
    s16x8 af[2][4];
#pragma unroll
    for (int m = 0; m < 2; ++m)
#pragma unroll
        for (int kk = 0; kk < 4; ++kk)
            af[m][kk] = *(const s16x8*)&fnp[(size_t)((rbase >> 4) + m) * 2048 + kk * 512 + lane * 8];

    __syncthreads();   // drains global_load_lds; half-panel ready

    float pd[2][4] = {};  // row partials across both tiles

#pragma unroll
    for (int t = 0; t < 2; ++t) {   // 2 tiles of 64 cols
        f32x4 acc[2][4] = {};
#pragma unroll
        for (int kk = 0; kk < 4; ++kk) {
            s16x8 bfr[4];
#pragma unroll
            for (int n = 0; n < 4; ++n)
                bfr[n] = *(const s16x8*)&ldsB[(size_t)(t * 4 + n) * 2048 + kk * 512 + lane * 8];
#pragma unroll
            for (int m = 0; m < 2; ++m)
#pragma unroll
                for (int n = 0; n < 4; ++n)
                    acc[m][n] = __builtin_amdgcn_mfma_f32_16x16x32_bf16(af[m][kk], bfr[n], acc[m][n], 0, 0, 0);
        }
        float pcn[4] = {0.f, 0.f, 0.f, 0.f};
#pragma unroll
        for (int m = 0; m < 2; ++m)
#pragma unroll
            for (int n = 0; n < 4; ++n)
#pragma unroll
                for (int r = 0; r < 4; ++r) {
                    const float e = fexp2(acc[m][n][r]);
                    pd[m][r] += e;
                    pcn[n] += e;
                }
        if (offd) {
#pragma unroll
            for (int n = 0; n < 4; ++n) {
                float v = pcn[n];
                v += __shfl_xor(v, 16);
                v += __shfl_xor(v, 32);
                if (lane < 16) colbuf[wv][t * 64 + n * 16 + lrow] = v;
            }
        }
    }

    // row partials -> slot 2J+h, plain store (wave owns its rows)
#pragma unroll
    for (int m = 0; m < 2; ++m)
#pragma unroll
        for (int r = 0; r < 4; ++r) {
            float v = pd[m][r];
#pragma unroll
            for (int msk = 1; msk < 16; msk <<= 1) v += __shfl_xor(v, msk, 16);
            if (lrow == 0)
                denomP[(size_t)(2 * J + h) * M_ROWS + rbase + m * 16 + g * 4 + r] = v;
        }

    // col partials: split by source-row half -> slots 2I / 2I+1 (block-uniform branch)
    if (offd) {
        __syncthreads();
        if (tid < 128) {
            const float cv0 = colbuf[0][tid] + colbuf[1][tid] + colbuf[2][tid] + colbuf[3][tid];
            const float cv1 = colbuf[4][tid] + colbuf[5][tid] + colbuf[6][tid] + colbuf[7][tid];
            const size_t cpos = (size_t)J * 256 + h * 128 + tid;
            denomP[(size_t)(2 * I) * M_ROWS + cpos] = cv0;
            denomP[(size_t)(2 * I + 1) * M_ROWS + cpos] = cv1;
        }
    }

    // ---- class-gather tail: blocks 0-59, one class each ----
    if (bid < NCLS) {
        const int c = bid;
        float a[8] = {0.f, 0.f, 0.f, 0.f, 0.f, 0.f, 0.f, 0.f};
        float cnt = 0.f;
        // 32 row-streams (wv*4+g), 16 k-lanes (lrow) each covering 8 dims
#pragma unroll 4
        for (int j = (tid >> 4); j < M_ROWS; j += 32) {
            if (labels[j] == c) {
                const s16x8 q = *(const s16x8*)&fnr[(size_t)j * K_DIM + lrow * 8];
#pragma unroll
                for (int i = 0; i < 8; ++i) a[i] += bf2f((ushort)q[i]);
                if (lrow == 0) cnt += 1.f;
            }
        }
#pragma unroll
        for (int i = 0; i < 8; ++i) {   // reduce the wave's 4 g-streams
            a[i] += __shfl_xor(a[i], 16);
            a[i] += __shfl_xor(a[i], 32);
        }
        cnt += __shfl_xor(cnt, 16);
        cnt += __shfl_xor(cnt, 32);
        if (g == 0) {
#pragma unroll
            for (int i = 0; i < 8; ++i) Sb[wv][lrow * 8 + i] = a[i];
        }
        if (lane == 0) Cb[wv] = cnt;
        __syncthreads();
        if (tid < K_DIM) {
            float s = 0.f;
#pragma unroll
            for (int w = 0; w < 8; ++w) s += Sb[w][tid];
            S[c * K_DIM + tid] = s;
        } else if (tid == K_DIM) {
            float s = 0.f;
#pragma unroll
            for (int w = 0; w < 8; ++w) s += Cb[w];
            cntC[c] = s;
        }
    }
}

// ---------------- K3: finalize: per-row loss, mean ----------------
__global__ __launch_bounds__(1024) void kfin(const ushort* __restrict__ fn,
                                             const int* __restrict__ labels,
                                             const float* __restrict__ denomP,
                                             const float* __restrict__ S,
                                             const float* __restrict__ cntC,
                                             float* __restrict__ out) {
    const int tid = threadIdx.x;
    const int wv = tid >> 6, lane = tid & 63;
    const int row = blockIdx.x * 16 + wv;
    const ushort2 qv = *(const ushort2*)&fn[(size_t)row * K_DIM + lane * 2];
    const float f0 = bf2f(qv.x), f1 = bf2f(qv.y);
    const int c = labels[row];
    const float2 sv = *(const float2*)&S[c * K_DIM + lane * 2];
    float dot = f0 * sv.x + f1 * sv.y;   // q_i . S_c  (includes self)
    float sii = f0 * f0 + f1 * f1;       // q_i . q_i
    // gather the 64 slot partials for this row (one per lane)
    float dsum = denomP[(size_t)lane * M_ROWS + row];
#pragma unroll
    for (int msk = 1; msk < 64; msk <<= 1) {
        dot += __shfl_xor(dot, msk, 64);
        sii += __shfl_xor(sii, msk, 64);
        dsum += __shfl_xor(dsum, msk, 64);
    }

    __shared__ float ls[16];
    if (lane == 0) {
        const float cf = cntC[c];                                   // count incl. self
        const float d = fmaxf(dsum - fexp2(sii), 1e-5f);            // exclude diagonal
        const float p = (dot - sii) * LN2;                          // matched sims, excl diag
        ls[wv] = ((cf - 1.f) * __logf(d) - p) / cf;
    }
    __syncthreads();
    if (tid == 0) {
        float s = 0.f;
#pragma unroll
        for (int i = 0; i < 16; ++i) s += ls[i];
        atomicAdd(out, s * (1.0f / M_ROWS));
    }
}

extern "C" void kernel_launch(void* const* d_in, const int* in_sizes, int n_in,
                              void* d_out, int out_size, void* d_ws, size_t ws_size,
                              hipStream_t stream) {
    (void)in_sizes; (void)n_in; (void)out_size; (void)ws_size;
    const float* feat = (const float*)d_in[0];
    const int* labels = (const int*)d_in[2];   // d_in[1] (ious) unused: coef == 1
    float* out = (float*)d_out;
    char* ws = (char*)d_ws;
    ushort* fnr = (ushort*)ws;                                  // 2 MB row-major bf16
    ushort* fnp = fnr + (size_t)M_ROWS * K_DIM;                 // 2 MB packed fragment-major
    float* denomP = (float*)(fnp + (size_t)M_ROWS * K_DIM);     // 64 x 8192 x 4B = 2 MB
    float* S = denomP + (size_t)NSLOT * M_ROWS;                 // 30 KB
    float* cntC = S + NCLS * K_DIM;                             // 256 B

    kprep<<<M_ROWS / 32, 256, 0, stream>>>(feat, fnr, fnp, out);
    kmain<<<NSIM * 2, 512, 0, stream>>>(fnp, fnr, labels, denomP, S, cntC);
    kfin<<<M_ROWS / 16, 1024, 0, stream>>>(fnr, labels, denomP, S, cntC, out);
}

// Round 21
// 50.383 us; speedup vs baseline: 1.4100x; 1.4100x over previous
//
#include <hip/hip_runtime.h>
#include <hip/hip_bf16.h>

#define M_ROWS 8192
#define K_DIM 128
#define NCLS 60
#define NSLOT 64           // 2 slots per 256-col panel; denomP is [row][slot] (transposed)
#define NSIM 528           // 32*33/2 upper-triangle panel pairs
#define NSLAB 256          // class partial tables (one per kprep block)

// x = q_i . q_j where q = bf16(fhat * SCL), SCL^2 = 5*log2(e)  ->  sim = x*ln2, exp(sim) = 2^x
constexpr float SCL = 2.68579007f;     // sqrt(5 * 1.4426950408889634)
constexpr float LN2 = 0.69314718056f;

using f32x4 = __attribute__((ext_vector_type(4))) float;
using s16x8 = __attribute__((ext_vector_type(8))) short;

__device__ inline float bf2f(ushort u) {
    union { unsigned int i; float f; } v; v.i = ((unsigned int)u) << 16; return v.f;
}
__device__ inline float fexp2(float x) {
#if __has_builtin(__builtin_amdgcn_exp2f)
    return __builtin_amdgcn_exp2f(x);
#else
    return exp2f(x);
#endif
}

// packed fragment-major layout: ushort index = c16*2048 + kk*512 + lane*8
//   (c16 = row/16 block, kk = k/32, lane = g*16+lrow; one MFMA fragment per 64-lane load)

// ---------------- K1: 256 blocks x 32 rows: normalize -> fnr + fnp; class slab from LDS ----------------
__global__ __launch_bounds__(256) void kprep(const float* __restrict__ feat,
                                             const int* __restrict__ labels,
                                             ushort* __restrict__ fnr,
                                             ushort* __restrict__ fnp,
                                             float* __restrict__ slabS,
                                             float* __restrict__ slabC,
                                             float* __restrict__ out) {
    __shared__ __align__(16) ushort ln[32][128];   // 8 KB
    __shared__ float Sl[NCLS * K_DIM];             // 30 KB
    __shared__ float Cl[NCLS];
    __shared__ int lab[32];
    const int tid = threadIdx.x, wv = tid >> 6, lane = tid & 63;
    const int rbase = blockIdx.x * 32;

    for (int i = tid; i < NCLS * K_DIM; i += 256) Sl[i] = 0.f;
    if (tid < NCLS) Cl[tid] = 0.f;
    if (tid < 32) lab[tid] = labels[rbase + tid];

    // ---- part A: normalize 32 rows (8 per wave) -> fnr + ln ----
#pragma unroll
    for (int it = 0; it < 8; ++it) {
        const int r = wv * 8 + it;
        const int grow = rbase + r;
        const float2 v = *(const float2*)&feat[(size_t)grow * K_DIM + lane * 2];
        float ss = v.x * v.x + v.y * v.y;
#pragma unroll
        for (int m = 1; m < 64; m <<= 1) ss += __shfl_xor(ss, m, 64);
        const float rs = rsqrtf(ss) * SCL;
        __hip_bfloat16 ha = __float2bfloat16(v.x * rs);
        __hip_bfloat16 hb = __float2bfloat16(v.y * rs);
        ushort2 o;
        o.x = *reinterpret_cast<const ushort*>(&ha);
        o.y = *reinterpret_cast<const ushort*>(&hb);
        *(ushort2*)&fnr[(size_t)grow * K_DIM + lane * 2] = o;
        *(ushort2*)&ln[r][lane * 2] = o;
    }
    __syncthreads();

    // ---- packed fnp: 2 row-groups of 16 ----
#pragma unroll
    for (int gb = 0; gb < 2; ++gb) {
        const s16x8 vv = *(const s16x8*)&ln[gb * 16 + (tid & 15)][(tid >> 4) * 8];
        *(s16x8*)&fnp[(size_t)(blockIdx.x * 2 + gb) * 2048 + tid * 8] = vv;
    }
    if (blockIdx.x == 0 && tid == 0) out[0] = 0.f;

    // ---- part B: class partials from the LDS-resident rows (no feat re-read) ----
    const int rsub = tid >> 4;   // 16 rows concurrent
    const int kc = tid & 15;     // 16 lanes x 8 bf16 = 128 k
#pragma unroll
    for (int it = 0; it < 2; ++it) {
        const int r = it * 16 + rsub;
        const int lb = lab[r];
        if (kc == 0) atomicAdd(&Cl[lb], 1.f);
        const s16x8 q = *(const s16x8*)&ln[r][kc * 8];
        float* dst = &Sl[lb * K_DIM + kc * 8];
#pragma unroll
        for (int j = 0; j < 8; ++j) atomicAdd(&dst[j], bf2f((ushort)q[j]));
    }
    __syncthreads();
    float* oS = slabS + (size_t)blockIdx.x * (NCLS * K_DIM);
    for (int i = tid; i < NCLS * K_DIM; i += 256) oS[i] = Sl[i];
    if (tid < NCLS) slabC[blockIdx.x * 64 + tid] = Cl[tid];
}

// ---------------- K2: half-panel blocks (I,J,h), 8 waves x 32 rows, LDS-staged ----------------
// 1056 blocks = 528 pairs x 2 col-halves. Row partials -> denomP[row][2J+h] (rows of I).
// Col partials (I<J): waves 0-3 -> slot 2I; waves 4-7 -> slot 2I+1, at rows J*256+h*128+0..127
// (adjacent slots -> one float2 store per thread). Every (row,slot) written exactly once.
__global__ __launch_bounds__(512) void kmain(const ushort* __restrict__ fnp,
                                             const float* __restrict__ slabS,
                                             const float* __restrict__ slabC,
                                             float* __restrict__ denomP,
                                             float* __restrict__ S,
                                             float* __restrict__ cntC) {
    __shared__ __align__(16) ushort ldsB[8 * 2048];   // 32 KB: half-panel, packed layout
    __shared__ float colbuf[8][128];                  // 4 KB
    const int tid = threadIdx.x;
    const int lane = tid & 63;
    const int lrow = lane & 15;
    const int g = lane >> 4;
    const int wv = tid >> 6;           // 0..7

    const int bid = blockIdx.x;
    const int p = bid >> 1;            // pair index 0..527
    const int h = bid & 1;             // column half
    // decode p -> (I, J), I <= J < 32; off(I) = 32I - I(I-1)/2
    int I = (int)((65.0f - sqrtf(4225.0f - 8.0f * (float)p)) * 0.5f);
    while ((I + 1) * 32 - ((I + 1) * I) / 2 <= p) ++I;
    while (I * 32 - (I * (I - 1)) / 2 > p) --I;
    const int J = I + (p - (I * 32 - (I * (I - 1)) / 2));
    const bool offd = (J != I);
    const int rbase = I * 256 + wv * 32;   // this wave's 32 rows

    // ---- stage half-panel (32 KB) into LDS; both sides linear ----
    {
        const ushort* gbase = fnp + (size_t)(J * 16 + h * 8) * 2048;
#pragma unroll
        for (int it = 0; it < 4; ++it) {
            const int chunk = it * 512 + wv * 64;      // wave-uniform; lane adds *16B
            const ushort* src = gbase + (size_t)(chunk + lane) * 8;
            ushort* dst = &ldsB[(size_t)chunk * 8];
            __builtin_amdgcn_global_load_lds((const __attribute__((address_space(1))) void*)src,
                                             (__attribute__((address_space(3))) void*)dst, 16, 0, 0);
        }
    }

    // persistent A fragments: rows rbase..+31, K=128 (packed, lane-linear, from global)
    s16x8 af[2][4];
#pragma unroll
    for (int m = 0; m < 2; ++m)
#pragma unroll
        for (int kk = 0; kk < 4; ++kk)
            af[m][kk] = *(const s16x8*)&fnp[(size_t)((rbase >> 4) + m) * 2048 + kk * 512 + lane * 8];

    __syncthreads();   // drains global_load_lds; half-panel ready

    float pd[2][4] = {};  // row partials across both tiles

#pragma unroll
    for (int t = 0; t < 2; ++t) {   // 2 tiles of 64 cols
        f32x4 acc[2][4] = {};
#pragma unroll
        for (int kk = 0; kk < 4; ++kk) {
            s16x8 bfr[4];
#pragma unroll
            for (int n = 0; n < 4; ++n)
                bfr[n] = *(const s16x8*)&ldsB[(size_t)(t * 4 + n) * 2048 + kk * 512 + lane * 8];
#pragma unroll
            for (int m = 0; m < 2; ++m)
#pragma unroll
                for (int n = 0; n < 4; ++n)
                    acc[m][n] = __builtin_amdgcn_mfma_f32_16x16x32_bf16(af[m][kk], bfr[n], acc[m][n], 0, 0, 0);
        }
        float pcn[4] = {0.f, 0.f, 0.f, 0.f};
#pragma unroll
        for (int m = 0; m < 2; ++m)
#pragma unroll
            for (int n = 0; n < 4; ++n)
#pragma unroll
                for (int r = 0; r < 4; ++r) {
                    const float e = fexp2(acc[m][n][r]);
                    pd[m][r] += e;
                    pcn[n] += e;
                }
        if (offd) {
#pragma unroll
            for (int n = 0; n < 4; ++n) {
                float v = pcn[n];
                v += __shfl_xor(v, 16);
                v += __shfl_xor(v, 32);
                if (lane < 16) colbuf[wv][t * 64 + n * 16 + lrow] = v;
            }
        }
    }

    // row partials -> denomP[row][2J+h], plain store (wave owns its rows)
#pragma unroll
    for (int m = 0; m < 2; ++m)
#pragma unroll
        for (int r = 0; r < 4; ++r) {
            float v = pd[m][r];
#pragma unroll
            for (int msk = 1; msk < 16; msk <<= 1) v += __shfl_xor(v, msk, 16);
            if (lrow == 0)
                denomP[(size_t)(rbase + m * 16 + g * 4 + r) * NSLOT + (2 * J + h)] = v;
        }

    // col partials: adjacent slots 2I/2I+1 -> one float2 per thread (block-uniform branch)
    if (offd) {
        __syncthreads();
        if (tid < 128) {
            const float cv0 = colbuf[0][tid] + colbuf[1][tid] + colbuf[2][tid] + colbuf[3][tid];
            const float cv1 = colbuf[4][tid] + colbuf[5][tid] + colbuf[6][tid] + colbuf[7][tid];
            const size_t crow = (size_t)J * 256 + h * 128 + tid;
            float2 cv; cv.x = cv0; cv.y = cv1;
            *(float2*)&denomP[crow * NSLOT + 2 * I] = cv;
        }
    }

    // tail: blocks 0-30 reduce slabs -> S, cntC
    if (bid < 31 && tid < 256) {
        const int i = bid * 256 + tid;
        if (i < NCLS * K_DIM) {
            float s = 0.f;
#pragma unroll 8
            for (int b = 0; b < NSLAB; ++b) s += slabS[(size_t)b * (NCLS * K_DIM) + i];
            S[i] = s;
        } else if (i < NCLS * K_DIM + NCLS) {
            const int c = i - NCLS * K_DIM;
            float s = 0.f;
#pragma unroll 8
            for (int b = 0; b < NSLAB; ++b) s += slabC[b * 64 + c];
            cntC[c] = s;
        }
    }
}

// ---------------- K3: finalize: per-row loss, mean (coalesced slot gather) ----------------
__global__ __launch_bounds__(1024) void kfin(const ushort* __restrict__ fn,
                                             const int* __restrict__ labels,
                                             const float* __restrict__ denomP,
                                             const float* __restrict__ S,
                                             const float* __restrict__ cntC,
                                             float* __restrict__ out) {
    const int tid = threadIdx.x;
    const int wv = tid >> 6, lane = tid & 63;
    const int row = blockIdx.x * 16 + wv;
    const ushort2 qv = *(const ushort2*)&fn[(size_t)row * K_DIM + lane * 2];
    const float f0 = bf2f(qv.x), f1 = bf2f(qv.y);
    const int c = labels[row];
    const float2 sv = *(const float2*)&S[c * K_DIM + lane * 2];
    float dot = f0 * sv.x + f1 * sv.y;   // q_i . S_c  (includes self)
    float sii = f0 * f0 + f1 * f1;       // q_i . q_i
    // coalesced: the 64 slot partials of this row are contiguous
    float dsum = denomP[(size_t)row * NSLOT + lane];
#pragma unroll
    for (int msk = 1; msk < 64; msk <<= 1) {
        dot += __shfl_xor(dot, msk, 64);
        sii += __shfl_xor(sii, msk, 64);
        dsum += __shfl_xor(dsum, msk, 64);
    }

    __shared__ float ls[16];
    if (lane == 0) {
        const float cf = cntC[c];                                   // count incl. self
        const float d = fmaxf(dsum - fexp2(sii), 1e-5f);            // exclude diagonal
        const float p = (dot - sii) * LN2;                          // matched sims, excl diag
        ls[wv] = ((cf - 1.f) * __logf(d) - p) / cf;
    }
    __syncthreads();
    if (tid == 0) {
        float s = 0.f;
#pragma unroll
        for (int i = 0; i < 16; ++i) s += ls[i];
        atomicAdd(out, s * (1.0f / M_ROWS));
    }
}

extern "C" void kernel_launch(void* const* d_in, const int* in_sizes, int n_in,
                              void* d_out, int out_size, void* d_ws, size_t ws_size,
                              hipStream_t stream) {
    (void)in_sizes; (void)n_in; (void)out_size; (void)ws_size;
    const float* feat = (const float*)d_in[0];
    const int* labels = (const int*)d_in[2];   // d_in[1] (ious) unused: coef == 1
    float* out = (float*)d_out;
    char* ws = (char*)d_ws;
    ushort* fnr = (ushort*)ws;                                  // 2 MB row-major bf16
    ushort* fnp = fnr + (size_t)M_ROWS * K_DIM;                 // 2 MB packed fragment-major
    float* denomP = (float*)(fnp + (size_t)M_ROWS * K_DIM);     // 8192 x 64 x 4B = 2 MB [row][slot]
    float* S = denomP + (size_t)M_ROWS * NSLOT;                 // 30 KB
    float* cntC = S + NCLS * K_DIM;                             // 256 B
    float* slabS = cntC + 64;                                   // 256 x 30 KB
    float* slabC = slabS + (size_t)NSLAB * NCLS * K_DIM;        // 256 x 256 B

    kprep<<<M_ROWS / 32, 256, 0, stream>>>(feat, labels, fnr, fnp, slabS, slabC, out);
    kmain<<<NSIM * 2, 512, 0, stream>>>(fnp, slabS, slabC, denomP, S, cntC);
    kfin<<<M_ROWS / 16, 1024, 0, stream>>>(fnr, labels, denomP, S, cntC, out);
}

// Round 22
// 49.397 us; speedup vs baseline: 1.4382x; 1.0200x over previous
//
#include <hip/hip_runtime.h>
#include <hip/hip_bf16.h>

#define M_ROWS 8192
#define K_DIM 128
#define NCLS 60
#define NSLOT 64           // 2 slots per 256-col panel; denomP is [row][slot]
#define NSIM 528           // 32*33/2 upper-triangle panel pairs
#define NSLAB 256          // class partial tables (one per kprep block)

// x = q_i . q_j where q = bf16(fhat * SCL), SCL^2 = 5*log2(e)  ->  sim = x*ln2, exp(sim) = 2^x
constexpr float SCL = 2.68579007f;     // sqrt(5 * 1.4426950408889634)
constexpr float LN2 = 0.69314718056f;

using f32x4 = __attribute__((ext_vector_type(4))) float;
using s16x8 = __attribute__((ext_vector_type(8))) short;

__device__ inline float bf2f(ushort u) {
    union { unsigned int i; float f; } v; v.i = ((unsigned int)u) << 16; return v.f;
}
__device__ inline float fexp2(float x) {
#if __has_builtin(__builtin_amdgcn_exp2f)
    return __builtin_amdgcn_exp2f(x);
#else
    return exp2f(x);
#endif
}

// packed fragment-major layout: ushort index = c16*2048 + kk*512 + lane*8
//   (c16 = row/16 block, kk = k/32, lane = g*16+lrow; one MFMA fragment per 64-lane load)

// ---------------- K1: 256 blocks x 32 rows: normalize -> fnr + fnp; class slab from LDS ----------------
__global__ __launch_bounds__(256) void kprep(const float* __restrict__ feat,
                                             const int* __restrict__ labels,
                                             ushort* __restrict__ fnr,
                                             ushort* __restrict__ fnp,
                                             float* __restrict__ slabS,
                                             float* __restrict__ slabC,
                                             float* __restrict__ out) {
    __shared__ __align__(16) ushort ln[32][128];   // 8 KB
    __shared__ float Sl[NCLS * K_DIM];             // 30 KB
    __shared__ float Cl[NCLS];
    __shared__ int lab[32];
    const int tid = threadIdx.x, wv = tid >> 6, lane = tid & 63;
    const int rbase = blockIdx.x * 32;

    for (int i = tid; i < NCLS * K_DIM; i += 256) Sl[i] = 0.f;
    if (tid < NCLS) Cl[tid] = 0.f;
    if (tid < 32) lab[tid] = labels[rbase + tid];

    // ---- part A: normalize 32 rows (8 per wave) -> fnr + ln ----
#pragma unroll
    for (int it = 0; it < 8; ++it) {
        const int r = wv * 8 + it;
        const int grow = rbase + r;
        const float2 v = *(const float2*)&feat[(size_t)grow * K_DIM + lane * 2];
        float ss = v.x * v.x + v.y * v.y;
#pragma unroll
        for (int m = 1; m < 64; m <<= 1) ss += __shfl_xor(ss, m, 64);
        const float rs = rsqrtf(ss) * SCL;
        __hip_bfloat16 ha = __float2bfloat16(v.x * rs);
        __hip_bfloat16 hb = __float2bfloat16(v.y * rs);
        ushort2 o;
        o.x = *reinterpret_cast<const ushort*>(&ha);
        o.y = *reinterpret_cast<const ushort*>(&hb);
        *(ushort2*)&fnr[(size_t)grow * K_DIM + lane * 2] = o;
        *(ushort2*)&ln[r][lane * 2] = o;
    }
    __syncthreads();

    // ---- packed fnp: 2 row-groups of 16 ----
#pragma unroll
    for (int gb = 0; gb < 2; ++gb) {
        const s16x8 vv = *(const s16x8*)&ln[gb * 16 + (tid & 15)][(tid >> 4) * 8];
        *(s16x8*)&fnp[(size_t)(blockIdx.x * 2 + gb) * 2048 + tid * 8] = vv;
    }
    if (blockIdx.x == 0 && tid == 0) out[0] = 0.f;

    // ---- part B: class partials from the LDS-resident rows ----
    const int rsub = tid >> 4;   // 16 rows concurrent
    const int kc = tid & 15;     // 16 lanes x 8 bf16 = 128 k
#pragma unroll
    for (int it = 0; it < 2; ++it) {
        const int r = it * 16 + rsub;
        const int lb = lab[r];
        if (kc == 0) atomicAdd(&Cl[lb], 1.f);
        const s16x8 q = *(const s16x8*)&ln[r][kc * 8];
        float* dst = &Sl[lb * K_DIM + kc * 8];
#pragma unroll
        for (int j = 0; j < 8; ++j) atomicAdd(&dst[j], bf2f((ushort)q[j]));
    }
    __syncthreads();
    float* oS = slabS + (size_t)blockIdx.x * (NCLS * K_DIM);
    for (int i = tid; i < NCLS * K_DIM; i += 256) oS[i] = Sl[i];
    if (tid < NCLS) slabC[blockIdx.x * 64 + tid] = Cl[tid];
}

// ---------------- K2: half-panel blocks, J-major task order + XCD-chunked mapping ----------------
// 1056 tasks = 528 pairs x 2 col-halves, J-major (same staged J-panel contiguous).
// blockIdx i -> task t = (i%8)*132 + i/8  (1056 = 8 XCDs x 132: same-J runs stay on one XCD's L2).
// Row partials -> denomP[row][2J+h]; col partials (I<J): waves 0-3 -> slot 2I, 4-7 -> 2I+1.
__global__ __launch_bounds__(512) void kmain(const ushort* __restrict__ fnp,
                                             const float* __restrict__ slabS,
                                             const float* __restrict__ slabC,
                                             float* __restrict__ denomP,
                                             float* __restrict__ S,
                                             float* __restrict__ cntC) {
    __shared__ __align__(16) ushort ldsB[8 * 2048];   // 32 KB: half-panel, packed layout
    __shared__ float colbuf[8][128];                  // 4 KB
    const int tid = threadIdx.x;
    const int lane = tid & 63;
    const int lrow = lane & 15;
    const int g = lane >> 4;
    const int wv = tid >> 6;           // 0..7

    const int bid = blockIdx.x;
    // XCD-chunked task remap: consecutive tasks (sharing a J panel) land on one XCD
    const int t = (bid & 7) * 132 + (bid >> 3);
    const int tp = t >> 1;             // pair index, J-major
    const int h = t & 1;               // column half
    // decode tp -> (J, I), I <= J < 32; off(J) = J(J+1)/2
    int J = (int)((sqrtf(8.0f * (float)tp + 1.0f) - 1.0f) * 0.5f);
    while ((J + 1) * (J + 2) / 2 <= tp) ++J;
    while (J * (J + 1) / 2 > tp) --J;
    const int I = tp - J * (J + 1) / 2;
    const bool offd = (J != I);
    const int rbase = I * 256 + wv * 32;   // this wave's 32 rows

    // ---- stage half-panel (32 KB) into LDS; both sides linear ----
    {
        const ushort* gbase = fnp + (size_t)(J * 16 + h * 8) * 2048;
#pragma unroll
        for (int it = 0; it < 4; ++it) {
            const int chunk = it * 512 + wv * 64;      // wave-uniform; lane adds *16B
            const ushort* src = gbase + (size_t)(chunk + lane) * 8;
            ushort* dst = &ldsB[(size_t)chunk * 8];
            __builtin_amdgcn_global_load_lds((const __attribute__((address_space(1))) void*)src,
                                             (__attribute__((address_space(3))) void*)dst, 16, 0, 0);
        }
    }

    // persistent A fragments: rows rbase..+31, K=128 (packed, lane-linear, from global)
    s16x8 af[2][4];
#pragma unroll
    for (int m = 0; m < 2; ++m)
#pragma unroll
        for (int kk = 0; kk < 4; ++kk)
            af[m][kk] = *(const s16x8*)&fnp[(size_t)((rbase >> 4) + m) * 2048 + kk * 512 + lane * 8];

    __syncthreads();   // drains global_load_lds; half-panel ready

    float pd[2][4] = {};  // row partials across both tiles

#pragma unroll
    for (int tt = 0; tt < 2; ++tt) {   // 2 tiles of 64 cols
        f32x4 acc[2][4] = {};
#pragma unroll
        for (int kk = 0; kk < 4; ++kk) {
            s16x8 bfr[4];
#pragma unroll
            for (int n = 0; n < 4; ++n)
                bfr[n] = *(const s16x8*)&ldsB[(size_t)(tt * 4 + n) * 2048 + kk * 512 + lane * 8];
#pragma unroll
            for (int m = 0; m < 2; ++m)
#pragma unroll
                for (int n = 0; n < 4; ++n)
                    acc[m][n] = __builtin_amdgcn_mfma_f32_16x16x32_bf16(af[m][kk], bfr[n], acc[m][n], 0, 0, 0);
        }
        float pcn[4] = {0.f, 0.f, 0.f, 0.f};
#pragma unroll
        for (int m = 0; m < 2; ++m)
#pragma unroll
            for (int n = 0; n < 4; ++n)
#pragma unroll
                for (int r = 0; r < 4; ++r) {
                    const float e = fexp2(acc[m][n][r]);
                    pd[m][r] += e;
                    pcn[n] += e;
                }
        if (offd) {
#pragma unroll
            for (int n = 0; n < 4; ++n) {
                float v = pcn[n];
                v += __shfl_xor(v, 16);
                v += __shfl_xor(v, 32);
                if (lane < 16) colbuf[wv][tt * 64 + n * 16 + lrow] = v;
            }
        }
    }

    // row partials -> denomP[row][2J+h], plain store (wave owns its rows)
#pragma unroll
    for (int m = 0; m < 2; ++m)
#pragma unroll
        for (int r = 0; r < 4; ++r) {
            float v = pd[m][r];
#pragma unroll
            for (int msk = 1; msk < 16; msk <<= 1) v += __shfl_xor(v, msk, 16);
            if (lrow == 0)
                denomP[(size_t)(rbase + m * 16 + g * 4 + r) * NSLOT + (2 * J + h)] = v;
        }

    // col partials: adjacent slots 2I/2I+1 -> one float2 per thread (block-uniform branch)
    if (offd) {
        __syncthreads();
        if (tid < 128) {
            const float cv0 = colbuf[0][tid] + colbuf[1][tid] + colbuf[2][tid] + colbuf[3][tid];
            const float cv1 = colbuf[4][tid] + colbuf[5][tid] + colbuf[6][tid] + colbuf[7][tid];
            const size_t crow = (size_t)J * 256 + h * 128 + tid;
            float2 cv; cv.x = cv0; cv.y = cv1;
            *(float2*)&denomP[crow * NSLOT + 2 * I] = cv;
        }
    }

    // tail: first-dispatched blocks 0-30 reduce slabs -> S, cntC
    if (bid < 31 && tid < 256) {
        const int i = bid * 256 + tid;
        if (i < NCLS * K_DIM) {
            float s = 0.f;
#pragma unroll 8
            for (int b = 0; b < NSLAB; ++b) s += slabS[(size_t)b * (NCLS * K_DIM) + i];
            S[i] = s;
        } else if (i < NCLS * K_DIM + NCLS) {
            const int c = i - NCLS * K_DIM;
            float s = 0.f;
#pragma unroll 8
            for (int b = 0; b < NSLAB; ++b) s += slabC[b * 64 + c];
            cntC[c] = s;
        }
    }
}

// ---------------- K3: finalize: per-row loss, mean (coalesced slot gather) ----------------
__global__ __launch_bounds__(1024) void kfin(const ushort* __restrict__ fn,
                                             const int* __restrict__ labels,
                                             const float* __restrict__ denomP,
                                             const float* __restrict__ S,
                                             const float* __restrict__ cntC,
                                             float* __restrict__ out) {
    const int tid = threadIdx.x;
    const int wv = tid >> 6, lane = tid & 63;
    const int row = blockIdx.x * 16 + wv;
    const ushort2 qv = *(const ushort2*)&fn[(size_t)row * K_DIM + lane * 2];
    const float f0 = bf2f(qv.x), f1 = bf2f(qv.y);
    const int c = labels[row];
    const float2 sv = *(const float2*)&S[c * K_DIM + lane * 2];
    float dot = f0 * sv.x + f1 * sv.y;   // q_i . S_c  (includes self)
    float sii = f0 * f0 + f1 * f1;       // q_i . q_i
    // coalesced: the 64 slot partials of this row are contiguous
    float dsum = denomP[(size_t)row * NSLOT + lane];
#pragma unroll
    for (int msk = 1; msk < 64; msk <<= 1) {
        dot += __shfl_xor(dot, msk, 64);
        sii += __shfl_xor(sii, msk, 64);
        dsum += __shfl_xor(dsum, msk, 64);
    }

    __shared__ float ls[16];
    if (lane == 0) {
        const float cf = cntC[c];                                   // count incl. self
        const float d = fmaxf(dsum - fexp2(sii), 1e-5f);            // exclude diagonal
        const float p = (dot - sii) * LN2;                          // matched sims, excl diag
        ls[wv] = ((cf - 1.f) * __logf(d) - p) / cf;
    }
    __syncthreads();
    if (tid == 0) {
        float s = 0.f;
#pragma unroll
        for (int i = 0; i < 16; ++i) s += ls[i];
        atomicAdd(out, s * (1.0f / M_ROWS));
    }
}

extern "C" void kernel_launch(void* const* d_in, const int* in_sizes, int n_in,
                              void* d_out, int out_size, void* d_ws, size_t ws_size,
                              hipStream_t stream) {
    (void)in_sizes; (void)n_in; (void)out_size; (void)ws_size;
    const float* feat = (const float*)d_in[0];
    const int* labels = (const int*)d_in[2];   // d_in[1] (ious) unused: coef == 1
    float* out = (float*)d_out;
    char* ws = (char*)d_ws;
    ushort* fnr = (ushort*)ws;                                  // 2 MB row-major bf16
    ushort* fnp = fnr + (size_t)M_ROWS * K_DIM;                 // 2 MB packed fragment-major
    float* denomP = (float*)(fnp + (size_t)M_ROWS * K_DIM);     // 8192 x 64 x 4B [row][slot]
    float* S = denomP + (size_t)M_ROWS * NSLOT;                 // 30 KB
    float* cntC = S + NCLS * K_DIM;                             // 256 B
    float* slabS = cntC + 64;                                   // 256 x 30 KB
    float* slabC = slabS + (size_t)NSLAB * NCLS * K_DIM;        // 256 x 256 B

    kprep<<<M_ROWS / 32, 256, 0, stream>>>(feat, labels, fnr, fnp, slabS, slabC, out);
    kmain<<<NSIM * 2, 512, 0, stream>>>(fnp, slabS, slabC, denomP, S, cntC);
    kfin<<<M_ROWS / 16, 1024, 0, stream>>>(fnr, labels, denomP, S, cntC, out);
}